// Round 11
// baseline (777.350 us; speedup 1.0000x reference)
//
#include <hip/hip_runtime.h>
#include <hip/hip_bf16.h>

#define IC 4096
#define OC 11008
#define MTOT 8192

#define BM 256
#define BN 256
#define BK 64
#define NT (IC / BK)      // 64 K-tiles
#define LDSBUF 65536      // one buffer: A 32 KB + B 32 KB
#define BOFF 32768

// Kernel A: bn 0..39 (cols 0..10239): 32x40 = 1280 blocks = exactly 5 rounds
#define NBN_A 40
#define NBLK_A 1280
// Kernel B: cols 10240..11007 with 128^2 tiles: 64x6 = 384 blocks
#define NBASE_B 10240
#define NBN_B 6
#define NBLK_B 384

typedef __attribute__((ext_vector_type(8))) short short8;
typedef __attribute__((ext_vector_type(4))) float floatx4;

__device__ __forceinline__ void async_copy16(const void* g, void* l) {
  __builtin_amdgcn_global_load_lds(
      (const __attribute__((address_space(1))) void*)g,
      (__attribute__((address_space(3))) void*)l, 16, 0, 0);
}

#define CFENCE() asm volatile("" ::: "memory")
#define BARRIER() do { CFENCE(); __builtin_amdgcn_s_barrier(); CFENCE(); } while (0)

// ---------------------------------------------------------------------------
// Pass 1a: x f32 -> bf16
// ---------------------------------------------------------------------------
__global__ __launch_bounds__(256) void cvt_x_kernel(
    const float* __restrict__ X, __hip_bfloat16* __restrict__ Xb) {
  size_t base = ((size_t)blockIdx.x * 256 + threadIdx.x) * 8;
  float4 a0 = *(const float4*)(X + base);
  float4 a1 = *(const float4*)(X + base + 4);
  union { __hip_bfloat16 h[8]; short8 v; } u;
  u.h[0] = __float2bfloat16(a0.x); u.h[1] = __float2bfloat16(a0.y);
  u.h[2] = __float2bfloat16(a0.z); u.h[3] = __float2bfloat16(a0.w);
  u.h[4] = __float2bfloat16(a1.x); u.h[5] = __float2bfloat16(a1.y);
  u.h[6] = __float2bfloat16(a1.z); u.h[7] = __float2bfloat16(a1.w);
  *(short8*)(Xb + base) = u.v;
}

// ---------------------------------------------------------------------------
// Pass 1b: dequant Q int32 -> bf16 W [OC][IC]
// ---------------------------------------------------------------------------
__global__ __launch_bounds__(256) void dequant_kernel(
    const int* __restrict__ Q, const float* __restrict__ scales,
    const float* __restrict__ zeros, __hip_bfloat16* __restrict__ W) {
  size_t base = ((size_t)blockIdx.x * 256 + threadIdx.x) * 8;
  int o = (int)(base >> 12);
  int g = ((int)(base & 4095)) >> 7;
  float s = scales[(size_t)g * OC + o];
  float z = zeros[(size_t)g * OC + o];
  int4 q0 = *(const int4*)(Q + base);
  int4 q1 = *(const int4*)(Q + base + 4);
  union { __hip_bfloat16 h[8]; short8 v; } u;
  u.h[0] = __float2bfloat16(fmaf((float)q0.x, s, z));
  u.h[1] = __float2bfloat16(fmaf((float)q0.y, s, z));
  u.h[2] = __float2bfloat16(fmaf((float)q0.z, s, z));
  u.h[3] = __float2bfloat16(fmaf((float)q0.w, s, z));
  u.h[4] = __float2bfloat16(fmaf((float)q1.x, s, z));
  u.h[5] = __float2bfloat16(fmaf((float)q1.y, s, z));
  u.h[6] = __float2bfloat16(fmaf((float)q1.z, s, z));
  u.h[7] = __float2bfloat16(fmaf((float)q1.w, s, z));
  *(short8*)(W + base) = u.v;
}

// ---------------------------------------------------------------------------
// Kernel A: 256x256x64 8-wave 4-phase pipelined GEMM (exact round-5 body),
// covering output cols 0..10239. Grid 1280 = 5.0 exact dispatch rounds.
// ---------------------------------------------------------------------------
__global__ __launch_bounds__(512, 2) void gemm_8phase(
    const __hip_bfloat16* __restrict__ A,   // [MTOT][IC] bf16
    const __hip_bfloat16* __restrict__ B,   // [OC][IC] bf16
    const float* __restrict__ bias,         // [OC] f32
    float* __restrict__ C) {                // [MTOT][OC] f32
  __shared__ char lds[2 * LDSBUF];          // 128 KB

  int bid = blockIdx.x;
  int swz = (bid & 7) * (NBLK_A >> 3) + (bid >> 3);  // bijective (1280=8*160)
  int bm = swz / NBN_A, bn = swz % NBN_A;
  const int m0 = bm * BM, n0 = bn * BN;

  const int tid  = threadIdx.x;
  const int lane = tid & 63;
  const int wid  = tid >> 6;
  const int wr = wid >> 2, wc = wid & 3;    // 2x4 wave grid; wave owns 128x64

  // staging geometry: unit = 64 rows x 128 B = 8 KB = 1 load/thread
  const int srl   = tid >> 3;               // row within unit (0..63)
  const int scph  = (tid & 7) << 4;         // physical col byte
  const int sclog = scph ^ ((srl & 7) << 4);// pre-swizzled logical col byte
  const size_t UROW = (size_t)64 * IC * 2;  // global byte stride per unit
  const int sdst = tid * 16;                // linear LDS dest within unit

  const char* gA = (const char*)A + ((size_t)(m0 + srl) * IC) * 2 + sclog;
  const char* gB = (const char*)B + ((size_t)(n0 + srl) * IC) * 2 + sclog;

  // fragment-read geometry (16x16x32; lane: row l&15, k (l>>4)*8)
  const int l15  = lane & 15;
  const int hi16 = ((lane >> 4) & 3) << 4;
  const int swzl = (lane & 7) << 4;
  const int ck0  = hi16 ^ swzl;             // col byte for kk=0 (kk=1: ^64)
  const int aRowB = (wr * 128 + l15) * 128; // row byte offset in A region
  const int bRowB = (wc * 64  + l15) * 128; // row byte offset in B region

  floatx4 acc[8][4];
#pragma unroll
  for (int i = 0; i < 8; ++i)
#pragma unroll
    for (int j = 0; j < 4; ++j)
      acc[i][j] = (floatx4){0.f, 0.f, 0.f, 0.f};

  // ---- prologue: tile0 complete (8 units) + tile1 partial (B0-3,A0,A2) ----
#pragma unroll
  for (int u = 0; u < 4; ++u)
    async_copy16(gA + u * UROW, lds + u * 8192 + sdst);
#pragma unroll
  for (int u = 0; u < 4; ++u)
    async_copy16(gB + u * UROW, lds + BOFF + u * 8192 + sdst);
#pragma unroll
  for (int u = 0; u < 4; ++u)
    async_copy16(gB + u * UROW + 128, lds + LDSBUF + BOFF + u * 8192 + sdst);
  async_copy16(gA + 0 * UROW + 128, lds + LDSBUF + 0 * 8192 + sdst);
  async_copy16(gA + 2 * UROW + 128, lds + LDSBUF + 2 * 8192 + sdst);
  asm volatile("s_waitcnt vmcnt(6)" ::: "memory");  // tile0 landed
  BARRIER();

  for (int t = 0; t < NT; ++t) {
    const int par = t & 1;
    char* curA = lds + par * LDSBUF;
    char* curB = curA + BOFF;
    char* nxtA = lds + (par ^ 1) * LDSBUF;
    const char* gAt1 = gA + (size_t)(t + 1) * 128;
    const char* gAt2 = gA + (size_t)(t + 2) * 128;
    const char* gBt2 = gB + (size_t)(t + 2) * 128;
    const bool s1 = (t + 1 < NT), s2 = (t + 2 < NT);

    const char* pa = curA + aRowB;
    const char* pb = curB + bRowB;
    short8 bfr[4][2];

#define MFMA16(P, AF0, AF1, AF2, AF3)                                        \
    BARRIER();                                                               \
    asm volatile("s_waitcnt lgkmcnt(0)" ::: "memory");                       \
    __builtin_amdgcn_s_setprio(1);                                           \
    _Pragma("unroll")                                                        \
    for (int fn = 0; fn < 4; ++fn) {                                         \
      acc[2*(P)][fn]   = __builtin_amdgcn_mfma_f32_16x16x32_bf16(            \
          AF0, bfr[fn][0], acc[2*(P)][fn], 0, 0, 0);                         \
      acc[2*(P)][fn]   = __builtin_amdgcn_mfma_f32_16x16x32_bf16(            \
          AF1, bfr[fn][1], acc[2*(P)][fn], 0, 0, 0);                         \
      acc[2*(P)+1][fn] = __builtin_amdgcn_mfma_f32_16x16x32_bf16(            \
          AF2, bfr[fn][0], acc[2*(P)+1][fn], 0, 0, 0);                       \
      acc[2*(P)+1][fn] = __builtin_amdgcn_mfma_f32_16x16x32_bf16(            \
          AF3, bfr[fn][1], acc[2*(P)+1][fn], 0, 0, 0);                       \
    }                                                                        \
    __builtin_amdgcn_s_setprio(0);

    // ---------- phase 0: fm 0-1; read all B frags; stage t+1 A1,A3 ----------
    {
      short8 a00 = *(const short8*)(pa + 0 * 2048 + ck0);
      short8 a01 = *(const short8*)(pa + 0 * 2048 + (ck0 ^ 64));
      short8 a10 = *(const short8*)(pa + 1 * 2048 + ck0);
      short8 a11 = *(const short8*)(pa + 1 * 2048 + (ck0 ^ 64));
#pragma unroll
      for (int fn = 0; fn < 4; ++fn) {
        bfr[fn][0] = *(const short8*)(pb + fn * 2048 + ck0);
        bfr[fn][1] = *(const short8*)(pb + fn * 2048 + (ck0 ^ 64));
      }
      if (s1) {
        async_copy16(gAt1 + 1 * UROW, nxtA + 1 * 8192 + sdst);
        async_copy16(gAt1 + 3 * UROW, nxtA + 3 * 8192 + sdst);
      }
      MFMA16(0, a00, a01, a10, a11);
      BARRIER();
    }
    // ---------- phase 1: fm 2-3; stage t+2 B0,B1 (B free after p0) ----------
    {
      short8 a00 = *(const short8*)(pa + 2 * 2048 + ck0);
      short8 a01 = *(const short8*)(pa + 2 * 2048 + (ck0 ^ 64));
      short8 a10 = *(const short8*)(pa + 3 * 2048 + ck0);
      short8 a11 = *(const short8*)(pa + 3 * 2048 + (ck0 ^ 64));
      if (s2) {
        async_copy16(gBt2 + 0 * UROW, curB + 0 * 8192 + sdst);
        async_copy16(gBt2 + 1 * UROW, curB + 1 * 8192 + sdst);
      }
      MFMA16(1, a00, a01, a10, a11);
      BARRIER();
    }
    // ---------- phase 2: fm 4-5; stage t+2 B2,B3 ----------
    {
      short8 a00 = *(const short8*)(pa + 4 * 2048 + ck0);
      short8 a01 = *(const short8*)(pa + 4 * 2048 + (ck0 ^ 64));
      short8 a10 = *(const short8*)(pa + 5 * 2048 + ck0);
      short8 a11 = *(const short8*)(pa + 5 * 2048 + (ck0 ^ 64));
      if (s2) {
        async_copy16(gBt2 + 2 * UROW, curB + 2 * 8192 + sdst);
        async_copy16(gBt2 + 3 * UROW, curB + 3 * 8192 + sdst);
      }
      MFMA16(2, a00, a01, a10, a11);
      BARRIER();
    }
    // ---------- phase 3: fm 6-7; stage t+2 A0,A2 ----------
    {
      short8 a00 = *(const short8*)(pa + 6 * 2048 + ck0);
      short8 a01 = *(const short8*)(pa + 6 * 2048 + (ck0 ^ 64));
      short8 a10 = *(const short8*)(pa + 7 * 2048 + ck0);
      short8 a11 = *(const short8*)(pa + 7 * 2048 + (ck0 ^ 64));
      if (s2) {
        async_copy16(gAt2 + 0 * UROW, curA + 0 * 8192 + sdst);
        async_copy16(gAt2 + 2 * UROW, curA + 2 * 8192 + sdst);
      }
      MFMA16(3, a00, a01, a10, a11);
      if (s2)      { asm volatile("s_waitcnt vmcnt(6)" ::: "memory"); }
      else if (s1) { asm volatile("s_waitcnt vmcnt(0)" ::: "memory"); }
      BARRIER();
    }
#undef MFMA16
  }

  // ---- epilogue: bias + f32 store ----
#pragma unroll
  for (int fn = 0; fn < 4; ++fn) {
    int n = n0 + wc * 64 + fn * 16 + l15;
    float bv = bias[n];
#pragma unroll
    for (int fm = 0; fm < 8; ++fm) {
      int mrow = m0 + wr * 128 + fm * 16 + ((lane >> 4) << 2);
#pragma unroll
      for (int j = 0; j < 4; ++j)
        C[(size_t)(mrow + j) * OC + n] = acc[fm][fn][j] + bv;
    }
  }
}

// ---------------------------------------------------------------------------
// Kernel B: 128x128 m97-structure GEMM (exact round-4 verified body) for the
// remaining output cols 10240..11007 (64 x 6 = 384 quarter-size blocks).
// ---------------------------------------------------------------------------
__global__ __launch_bounds__(256) void gemm_bt_tail(
    const __hip_bfloat16* __restrict__ A,   // [8192][4096] bf16
    const __hip_bfloat16* __restrict__ B,   // [11008][4096] bf16
    const float* __restrict__ bias,         // [11008] f32
    float* __restrict__ C) {                // [8192][11008] f32
  __shared__ __hip_bfloat16 As[128 * 32];   // 8 KB, linear [row][k]
  __shared__ __hip_bfloat16 Bs[128 * 32];   // 8 KB, linear [n][k]

  int bid = blockIdx.x;
  int swz = (bid & 7) * (NBLK_B >> 3) + (bid >> 3);  // bijective (384=8*48)
  int bm = swz / NBN_B, bn = swz % NBN_B;
  const int m0 = bm * 128, n0 = NBASE_B + bn * 128;

  const int tid = threadIdx.x;
  const int wid = tid >> 6, lane = tid & 63;
  const int wr = wid >> 1, wc = wid & 1;    // wave -> 64x64 sub-tile

  const int srow = lane >> 2;               // row within 16-row segment
  const int scol = (lane & 3) * 8;          // k element offset

  const int a_row = wr * 64 + (lane & 15);
  const int b_row = wc * 64 + (lane & 15);
  const int frag_kb = (lane >> 4) * 16;

  floatx4 acc[4][4];
#pragma unroll
  for (int i = 0; i < 4; ++i)
#pragma unroll
    for (int j = 0; j < 4; ++j)
      acc[i][j] = (floatx4){0.f, 0.f, 0.f, 0.f};

  for (int k0 = 0; k0 < IC; k0 += 32) {
#pragma unroll
    for (int i = 0; i < 2; ++i) {
      int s = wid * 2 + i;                  // segment 0..7
      const __hip_bfloat16* ga =
          A + (size_t)(m0 + s * 16 + srow) * IC + k0 + scol;
      async_copy16(ga, (char*)As + s * 1024);
      const __hip_bfloat16* gb =
          B + (size_t)(n0 + s * 16 + srow) * IC + k0 + scol;
      async_copy16(gb, (char*)Bs + s * 1024);
    }
    __syncthreads();

    short8 af[4], bf[4];
#pragma unroll
    for (int fm = 0; fm < 4; ++fm)
      af[fm] = *(const short8*)((const char*)As + (a_row + fm * 16) * 64 + frag_kb);
#pragma unroll
    for (int fn = 0; fn < 4; ++fn)
      bf[fn] = *(const short8*)((const char*)Bs + (b_row + fn * 16) * 64 + frag_kb);

#pragma unroll
    for (int fm = 0; fm < 4; ++fm)
#pragma unroll
      for (int fn = 0; fn < 4; ++fn)
        acc[fm][fn] = __builtin_amdgcn_mfma_f32_16x16x32_bf16(
            af[fm], bf[fn], acc[fm][fn], 0, 0, 0);

    __syncthreads();
  }

#pragma unroll
  for (int fn = 0; fn < 4; ++fn) {
    int n = n0 + wc * 64 + fn * 16 + (lane & 15);
    float bv = bias[n];
#pragma unroll
    for (int fm = 0; fm < 4; ++fm) {
      int mrow = m0 + wr * 64 + fm * 16 + (lane >> 4) * 4;
#pragma unroll
      for (int j = 0; j < 4; ++j)
        C[(size_t)(mrow + j) * OC + n] = acc[fm][fn][j] + bv;
    }
  }
}

// ---------------------------------------------------------------------------
// Fallback (ws too small): round-3 verified fused kernel
// ---------------------------------------------------------------------------
__global__ __launch_bounds__(256) void w4_gemm_fused_f32(
    const float* __restrict__ A, const int* __restrict__ Q,
    const float* __restrict__ scales, const float* __restrict__ zeros,
    const float* __restrict__ bias, float* __restrict__ C) {
  __shared__ __hip_bfloat16 As[128 * 32];
  __shared__ __hip_bfloat16 Bs[128 * 32];
  const int NBN = OC / 128;
  const int NBLK = (MTOT / 128) * NBN;
  int bid = blockIdx.x;
  int swz = (bid & 7) * (NBLK >> 3) + (bid >> 3);
  int bm = swz / NBN, bn = swz % NBN;
  const int m0 = bm * 128, n0 = bn * 128;
  const int tid = threadIdx.x;
  const int wid = tid >> 6, lane = tid & 63;
  const int wr = wid >> 1, wc = wid & 1;
  const int row = tid >> 1;
  const int kh  = (tid & 1) * 16;
  const float* arow = A + (size_t)(m0 + row) * IC + kh;
  const int*   qrow = Q + (size_t)(n0 + row) * IC + kh;
  const int    nrow = n0 + row;
  const int a_row = wr * 64 + (lane & 15);
  const int b_row = wc * 64 + (lane & 15);
  const int frag_kb = (lane >> 4) * 16;
  floatx4 acc[4][4];
#pragma unroll
  for (int i = 0; i < 4; ++i)
#pragma unroll
    for (int j = 0; j < 4; ++j)
      acc[i][j] = (floatx4){0.f, 0.f, 0.f, 0.f};
  for (int k0 = 0; k0 < IC; k0 += 32) {
    float4 a0 = *(const float4*)(arow + k0);
    float4 a1 = *(const float4*)(arow + k0 + 4);
    float4 a2 = *(const float4*)(arow + k0 + 8);
    float4 a3 = *(const float4*)(arow + k0 + 12);
    int4 q0 = *(const int4*)(qrow + k0);
    int4 q1 = *(const int4*)(qrow + k0 + 4);
    int4 q2 = *(const int4*)(qrow + k0 + 8);
    int4 q3 = *(const int4*)(qrow + k0 + 12);
    int g = k0 >> 7;
    float s = scales[(size_t)g * OC + nrow];
    float z = zeros[(size_t)g * OC + nrow];
    union { __hip_bfloat16 h[16]; short8 v[2]; } ua, ub;
    ua.h[0]=__float2bfloat16(a0.x); ua.h[1]=__float2bfloat16(a0.y);
    ua.h[2]=__float2bfloat16(a0.z); ua.h[3]=__float2bfloat16(a0.w);
    ua.h[4]=__float2bfloat16(a1.x); ua.h[5]=__float2bfloat16(a1.y);
    ua.h[6]=__float2bfloat16(a1.z); ua.h[7]=__float2bfloat16(a1.w);
    ua.h[8]=__float2bfloat16(a2.x); ua.h[9]=__float2bfloat16(a2.y);
    ua.h[10]=__float2bfloat16(a2.z); ua.h[11]=__float2bfloat16(a2.w);
    ua.h[12]=__float2bfloat16(a3.x); ua.h[13]=__float2bfloat16(a3.y);
    ua.h[14]=__float2bfloat16(a3.z); ua.h[15]=__float2bfloat16(a3.w);
    ub.h[0]=__float2bfloat16(fmaf((float)q0.x,s,z));
    ub.h[1]=__float2bfloat16(fmaf((float)q0.y,s,z));
    ub.h[2]=__float2bfloat16(fmaf((float)q0.z,s,z));
    ub.h[3]=__float2bfloat16(fmaf((float)q0.w,s,z));
    ub.h[4]=__float2bfloat16(fmaf((float)q1.x,s,z));
    ub.h[5]=__float2bfloat16(fmaf((float)q1.y,s,z));
    ub.h[6]=__float2bfloat16(fmaf((float)q1.z,s,z));
    ub.h[7]=__float2bfloat16(fmaf((float)q1.w,s,z));
    ub.h[8]=__float2bfloat16(fmaf((float)q2.x,s,z));
    ub.h[9]=__float2bfloat16(fmaf((float)q2.y,s,z));
    ub.h[10]=__float2bfloat16(fmaf((float)q2.z,s,z));
    ub.h[11]=__float2bfloat16(fmaf((float)q2.w,s,z));
    ub.h[12]=__float2bfloat16(fmaf((float)q3.x,s,z));
    ub.h[13]=__float2bfloat16(fmaf((float)q3.y,s,z));
    ub.h[14]=__float2bfloat16(fmaf((float)q3.z,s,z));
    ub.h[15]=__float2bfloat16(fmaf((float)q3.w,s,z));
    *(short8*)(&As[row * 32 + kh])     = ua.v[0];
    *(short8*)(&As[row * 32 + kh + 8]) = ua.v[1];
    *(short8*)(&Bs[row * 32 + kh])     = ub.v[0];
    *(short8*)(&Bs[row * 32 + kh + 8]) = ub.v[1];
    __syncthreads();
    short8 af[4], bf[4];
#pragma unroll
    for (int fm = 0; fm < 4; ++fm)
      af[fm] = *(const short8*)((const char*)As + (a_row + fm*16)*64 + frag_kb);
#pragma unroll
    for (int fn = 0; fn < 4; ++fn)
      bf[fn] = *(const short8*)((const char*)Bs + (b_row + fn*16)*64 + frag_kb);
#pragma unroll
    for (int fm = 0; fm < 4; ++fm)
#pragma unroll
      for (int fn = 0; fn < 4; ++fn)
        acc[fm][fn] = __builtin_amdgcn_mfma_f32_16x16x32_bf16(
            af[fm], bf[fn], acc[fm][fn], 0, 0, 0);
    __syncthreads();
  }
#pragma unroll
  for (int fn = 0; fn < 4; ++fn) {
    int n = n0 + wc * 64 + fn * 16 + (lane & 15);
    float bv = bias[n];
#pragma unroll
    for (int fm = 0; fm < 4; ++fm) {
      int mrow = m0 + wr * 64 + fm * 16 + (lane >> 4) * 4;
#pragma unroll
      for (int j = 0; j < 4; ++j)
        C[(size_t)(mrow + j) * OC + n] = acc[fm][fn][j] + bv;
    }
  }
}

extern "C" void kernel_launch(void* const* d_in, const int* in_sizes, int n_in,
                              void* d_out, int out_size, void* d_ws, size_t ws_size,
                              hipStream_t stream) {
  const float* x      = (const float*)d_in[0];
  const int*   qw     = (const int*)d_in[1];
  const float* scales = (const float*)d_in[2];
  const float* szeros = (const float*)d_in[3];
  const float* bias   = (const float*)d_in[4];
  float* out = (float*)d_out;

  const size_t wbytes = (size_t)OC * IC * 2;
  const size_t xbytes = (size_t)MTOT * IC * 2;

  if (ws_size >= wbytes + xbytes) {
    __hip_bfloat16* W  = (__hip_bfloat16*)d_ws;
    __hip_bfloat16* Xb = (__hip_bfloat16*)((char*)d_ws + wbytes);
    cvt_x_kernel<<<16384, 256, 0, stream>>>(x, Xb);
    dequant_kernel<<<22016, 256, 0, stream>>>(qw, scales, szeros, W);
    // Tail kernel first (tiny), then the exact-fit 5-round main kernel.
    gemm_bt_tail<<<NBLK_B, 256, 0, stream>>>(Xb, W, bias, out);
    gemm_8phase<<<NBLK_A, 512, 0, stream>>>(Xb, W, bias, out);
  } else {
    w4_gemm_fused_f32<<<5504, 256, 0, stream>>>(x, qw, scales, szeros, bias, out);
  }
}

// Round 12
// 772.767 us; speedup vs baseline: 1.0059x; 1.0059x over previous
//
#include <hip/hip_runtime.h>
#include <hip/hip_bf16.h>

#define IC 4096
#define OC 11008
#define MTOT 8192

#define BM 256
#define BN 256
#define BK 64
#define NT (IC / BK)      // 64 K-tiles
#define LDSBUF 65536      // one buffer: A 32 KB + B 32 KB
#define BOFF 32768

// Kernel A: bn 0..39 (cols 0..10239): 32x40 = 1280 blocks = exactly 5 rounds
#define NBN_A 40
#define NBLK_A 1280
// Kernel B: cols 10240..11007 with 128^2 tiles: 64x6 = 384 blocks
#define NBASE_B 10240
#define NBN_B 6
#define NBLK_B 384

typedef __attribute__((ext_vector_type(8))) short short8;
typedef __attribute__((ext_vector_type(4))) float floatx4;

__device__ __forceinline__ void async_copy16(const void* g, void* l) {
  __builtin_amdgcn_global_load_lds(
      (const __attribute__((address_space(1))) void*)g,
      (__attribute__((address_space(3))) void*)l, 16, 0, 0);
}

#define CFENCE() asm volatile("" ::: "memory")
#define BARRIER() do { CFENCE(); __builtin_amdgcn_s_barrier(); CFENCE(); } while (0)

// ---------------------------------------------------------------------------
// Pass 1a: x f32 -> bf16   (normal stores: we WANT Xb resident in L3)
// ---------------------------------------------------------------------------
__global__ __launch_bounds__(256) void cvt_x_kernel(
    const float* __restrict__ X, __hip_bfloat16* __restrict__ Xb) {
  size_t base = ((size_t)blockIdx.x * 256 + threadIdx.x) * 8;
  float4 a0 = *(const float4*)(X + base);
  float4 a1 = *(const float4*)(X + base + 4);
  union { __hip_bfloat16 h[8]; short8 v; } u;
  u.h[0] = __float2bfloat16(a0.x); u.h[1] = __float2bfloat16(a0.y);
  u.h[2] = __float2bfloat16(a0.z); u.h[3] = __float2bfloat16(a0.w);
  u.h[4] = __float2bfloat16(a1.x); u.h[5] = __float2bfloat16(a1.y);
  u.h[6] = __float2bfloat16(a1.z); u.h[7] = __float2bfloat16(a1.w);
  *(short8*)(Xb + base) = u.v;
}

// ---------------------------------------------------------------------------
// Pass 1b: dequant Q int32 -> bf16 W [OC][IC]  (normal stores, keep in L3)
// ---------------------------------------------------------------------------
__global__ __launch_bounds__(256) void dequant_kernel(
    const int* __restrict__ Q, const float* __restrict__ scales,
    const float* __restrict__ zeros, __hip_bfloat16* __restrict__ W) {
  size_t base = ((size_t)blockIdx.x * 256 + threadIdx.x) * 8;
  int o = (int)(base >> 12);
  int g = ((int)(base & 4095)) >> 7;
  float s = scales[(size_t)g * OC + o];
  float z = zeros[(size_t)g * OC + o];
  int4 q0 = *(const int4*)(Q + base);
  int4 q1 = *(const int4*)(Q + base + 4);
  union { __hip_bfloat16 h[8]; short8 v; } u;
  u.h[0] = __float2bfloat16(fmaf((float)q0.x, s, z));
  u.h[1] = __float2bfloat16(fmaf((float)q0.y, s, z));
  u.h[2] = __float2bfloat16(fmaf((float)q0.z, s, z));
  u.h[3] = __float2bfloat16(fmaf((float)q0.w, s, z));
  u.h[4] = __float2bfloat16(fmaf((float)q1.x, s, z));
  u.h[5] = __float2bfloat16(fmaf((float)q1.y, s, z));
  u.h[6] = __float2bfloat16(fmaf((float)q1.z, s, z));
  u.h[7] = __float2bfloat16(fmaf((float)q1.w, s, z));
  *(short8*)(W + base) = u.v;
}

// ---------------------------------------------------------------------------
// Kernel A: 256x256x64 8-wave 4-phase pipelined GEMM (round-5 body),
// cols 0..10239, grid 1280 = 5.0 exact rounds. C stores NON-TEMPORAL so the
// 360 MB output stream doesn't evict the L3-resident Xb+W working set.
// ---------------------------------------------------------------------------
__global__ __launch_bounds__(512, 2) void gemm_8phase(
    const __hip_bfloat16* __restrict__ A,   // [MTOT][IC] bf16
    const __hip_bfloat16* __restrict__ B,   // [OC][IC] bf16
    const float* __restrict__ bias,         // [OC] f32
    float* __restrict__ C) {                // [MTOT][OC] f32
  __shared__ char lds[2 * LDSBUF];          // 128 KB

  int bid = blockIdx.x;
  int swz = (bid & 7) * (NBLK_A >> 3) + (bid >> 3);  // bijective (1280=8*160)
  int bm = swz / NBN_A, bn = swz % NBN_A;
  const int m0 = bm * BM, n0 = bn * BN;

  const int tid  = threadIdx.x;
  const int lane = tid & 63;
  const int wid  = tid >> 6;
  const int wr = wid >> 2, wc = wid & 3;    // 2x4 wave grid; wave owns 128x64

  // staging geometry: unit = 64 rows x 128 B = 8 KB = 1 load/thread
  const int srl   = tid >> 3;               // row within unit (0..63)
  const int scph  = (tid & 7) << 4;         // physical col byte
  const int sclog = scph ^ ((srl & 7) << 4);// pre-swizzled logical col byte
  const size_t UROW = (size_t)64 * IC * 2;  // global byte stride per unit
  const int sdst = tid * 16;                // linear LDS dest within unit

  const char* gA = (const char*)A + ((size_t)(m0 + srl) * IC) * 2 + sclog;
  const char* gB = (const char*)B + ((size_t)(n0 + srl) * IC) * 2 + sclog;

  // fragment-read geometry (16x16x32; lane: row l&15, k (l>>4)*8)
  const int l15  = lane & 15;
  const int hi16 = ((lane >> 4) & 3) << 4;
  const int swzl = (lane & 7) << 4;
  const int ck0  = hi16 ^ swzl;             // col byte for kk=0 (kk=1: ^64)
  const int aRowB = (wr * 128 + l15) * 128; // row byte offset in A region
  const int bRowB = (wc * 64  + l15) * 128; // row byte offset in B region

  floatx4 acc[8][4];
#pragma unroll
  for (int i = 0; i < 8; ++i)
#pragma unroll
    for (int j = 0; j < 4; ++j)
      acc[i][j] = (floatx4){0.f, 0.f, 0.f, 0.f};

  // ---- prologue: tile0 complete (8 units) + tile1 partial (B0-3,A0,A2) ----
#pragma unroll
  for (int u = 0; u < 4; ++u)
    async_copy16(gA + u * UROW, lds + u * 8192 + sdst);
#pragma unroll
  for (int u = 0; u < 4; ++u)
    async_copy16(gB + u * UROW, lds + BOFF + u * 8192 + sdst);
#pragma unroll
  for (int u = 0; u < 4; ++u)
    async_copy16(gB + u * UROW + 128, lds + LDSBUF + BOFF + u * 8192 + sdst);
  async_copy16(gA + 0 * UROW + 128, lds + LDSBUF + 0 * 8192 + sdst);
  async_copy16(gA + 2 * UROW + 128, lds + LDSBUF + 2 * 8192 + sdst);
  asm volatile("s_waitcnt vmcnt(6)" ::: "memory");  // tile0 landed
  BARRIER();

  for (int t = 0; t < NT; ++t) {
    const int par = t & 1;
    char* curA = lds + par * LDSBUF;
    char* curB = curA + BOFF;
    char* nxtA = lds + (par ^ 1) * LDSBUF;
    const char* gAt1 = gA + (size_t)(t + 1) * 128;
    const char* gAt2 = gA + (size_t)(t + 2) * 128;
    const char* gBt2 = gB + (size_t)(t + 2) * 128;
    const bool s1 = (t + 1 < NT), s2 = (t + 2 < NT);

    const char* pa = curA + aRowB;
    const char* pb = curB + bRowB;
    short8 bfr[4][2];

#define MFMA16(P, AF0, AF1, AF2, AF3)                                        \
    BARRIER();                                                               \
    asm volatile("s_waitcnt lgkmcnt(0)" ::: "memory");                       \
    __builtin_amdgcn_s_setprio(1);                                           \
    _Pragma("unroll")                                                        \
    for (int fn = 0; fn < 4; ++fn) {                                         \
      acc[2*(P)][fn]   = __builtin_amdgcn_mfma_f32_16x16x32_bf16(            \
          AF0, bfr[fn][0], acc[2*(P)][fn], 0, 0, 0);                         \
      acc[2*(P)][fn]   = __builtin_amdgcn_mfma_f32_16x16x32_bf16(            \
          AF1, bfr[fn][1], acc[2*(P)][fn], 0, 0, 0);                         \
      acc[2*(P)+1][fn] = __builtin_amdgcn_mfma_f32_16x16x32_bf16(            \
          AF2, bfr[fn][0], acc[2*(P)+1][fn], 0, 0, 0);                       \
      acc[2*(P)+1][fn] = __builtin_amdgcn_mfma_f32_16x16x32_bf16(            \
          AF3, bfr[fn][1], acc[2*(P)+1][fn], 0, 0, 0);                       \
    }                                                                        \
    __builtin_amdgcn_s_setprio(0);

    // ---------- phase 0: fm 0-1; read all B frags; stage t+1 A1,A3 ----------
    {
      short8 a00 = *(const short8*)(pa + 0 * 2048 + ck0);
      short8 a01 = *(const short8*)(pa + 0 * 2048 + (ck0 ^ 64));
      short8 a10 = *(const short8*)(pa + 1 * 2048 + ck0);
      short8 a11 = *(const short8*)(pa + 1 * 2048 + (ck0 ^ 64));
#pragma unroll
      for (int fn = 0; fn < 4; ++fn) {
        bfr[fn][0] = *(const short8*)(pb + fn * 2048 + ck0);
        bfr[fn][1] = *(const short8*)(pb + fn * 2048 + (ck0 ^ 64));
      }
      if (s1) {
        async_copy16(gAt1 + 1 * UROW, nxtA + 1 * 8192 + sdst);
        async_copy16(gAt1 + 3 * UROW, nxtA + 3 * 8192 + sdst);
      }
      MFMA16(0, a00, a01, a10, a11);
      BARRIER();
    }
    // ---------- phase 1: fm 2-3; stage t+2 B0,B1 (B free after p0) ----------
    {
      short8 a00 = *(const short8*)(pa + 2 * 2048 + ck0);
      short8 a01 = *(const short8*)(pa + 2 * 2048 + (ck0 ^ 64));
      short8 a10 = *(const short8*)(pa + 3 * 2048 + ck0);
      short8 a11 = *(const short8*)(pa + 3 * 2048 + (ck0 ^ 64));
      if (s2) {
        async_copy16(gBt2 + 0 * UROW, curB + 0 * 8192 + sdst);
        async_copy16(gBt2 + 1 * UROW, curB + 1 * 8192 + sdst);
      }
      MFMA16(1, a00, a01, a10, a11);
      BARRIER();
    }
    // ---------- phase 2: fm 4-5; stage t+2 B2,B3 ----------
    {
      short8 a00 = *(const short8*)(pa + 4 * 2048 + ck0);
      short8 a01 = *(const short8*)(pa + 4 * 2048 + (ck0 ^ 64));
      short8 a10 = *(const short8*)(pa + 5 * 2048 + ck0);
      short8 a11 = *(const short8*)(pa + 5 * 2048 + (ck0 ^ 64));
      if (s2) {
        async_copy16(gBt2 + 2 * UROW, curB + 2 * 8192 + sdst);
        async_copy16(gBt2 + 3 * UROW, curB + 3 * 8192 + sdst);
      }
      MFMA16(2, a00, a01, a10, a11);
      BARRIER();
    }
    // ---------- phase 3: fm 6-7; stage t+2 A0,A2 ----------
    {
      short8 a00 = *(const short8*)(pa + 6 * 2048 + ck0);
      short8 a01 = *(const short8*)(pa + 6 * 2048 + (ck0 ^ 64));
      short8 a10 = *(const short8*)(pa + 7 * 2048 + ck0);
      short8 a11 = *(const short8*)(pa + 7 * 2048 + (ck0 ^ 64));
      if (s2) {
        async_copy16(gAt2 + 0 * UROW, curA + 0 * 8192 + sdst);
        async_copy16(gAt2 + 2 * UROW, curA + 2 * 8192 + sdst);
      }
      MFMA16(3, a00, a01, a10, a11);
      if (s2)      { asm volatile("s_waitcnt vmcnt(6)" ::: "memory"); }
      else if (s1) { asm volatile("s_waitcnt vmcnt(0)" ::: "memory"); }
      BARRIER();
    }
#undef MFMA16
  }

  // ---- epilogue: bias + f32 NON-TEMPORAL store (bypass L3) ----
#pragma unroll
  for (int fn = 0; fn < 4; ++fn) {
    int n = n0 + wc * 64 + fn * 16 + l15;
    float bv = bias[n];
#pragma unroll
    for (int fm = 0; fm < 8; ++fm) {
      int mrow = m0 + wr * 128 + fm * 16 + ((lane >> 4) << 2);
#pragma unroll
      for (int j = 0; j < 4; ++j)
        __builtin_nontemporal_store(acc[fm][fn][j] + bv,
                                    &C[(size_t)(mrow + j) * OC + n]);
    }
  }
}

// ---------------------------------------------------------------------------
// Kernel B: 128x128 m97-structure GEMM for cols 10240..11007 (nt C-stores).
// ---------------------------------------------------------------------------
__global__ __launch_bounds__(256) void gemm_bt_tail(
    const __hip_bfloat16* __restrict__ A,
    const __hip_bfloat16* __restrict__ B,
    const float* __restrict__ bias,
    float* __restrict__ C) {
  __shared__ __hip_bfloat16 As[128 * 32];
  __shared__ __hip_bfloat16 Bs[128 * 32];

  int bid = blockIdx.x;
  int swz = (bid & 7) * (NBLK_B >> 3) + (bid >> 3);  // bijective (384=8*48)
  int bm = swz / NBN_B, bn = swz % NBN_B;
  const int m0 = bm * 128, n0 = NBASE_B + bn * 128;

  const int tid = threadIdx.x;
  const int wid = tid >> 6, lane = tid & 63;
  const int wr = wid >> 1, wc = wid & 1;

  const int srow = lane >> 2;
  const int scol = (lane & 3) * 8;

  const int a_row = wr * 64 + (lane & 15);
  const int b_row = wc * 64 + (lane & 15);
  const int frag_kb = (lane >> 4) * 16;

  floatx4 acc[4][4];
#pragma unroll
  for (int i = 0; i < 4; ++i)
#pragma unroll
    for (int j = 0; j < 4; ++j)
      acc[i][j] = (floatx4){0.f, 0.f, 0.f, 0.f};

  for (int k0 = 0; k0 < IC; k0 += 32) {
#pragma unroll
    for (int i = 0; i < 2; ++i) {
      int s = wid * 2 + i;
      const __hip_bfloat16* ga =
          A + (size_t)(m0 + s * 16 + srow) * IC + k0 + scol;
      async_copy16(ga, (char*)As + s * 1024);
      const __hip_bfloat16* gb =
          B + (size_t)(n0 + s * 16 + srow) * IC + k0 + scol;
      async_copy16(gb, (char*)Bs + s * 1024);
    }
    __syncthreads();

    short8 af[4], bf[4];
#pragma unroll
    for (int fm = 0; fm < 4; ++fm)
      af[fm] = *(const short8*)((const char*)As + (a_row + fm * 16) * 64 + frag_kb);
#pragma unroll
    for (int fn = 0; fn < 4; ++fn)
      bf[fn] = *(const short8*)((const char*)Bs + (b_row + fn * 16) * 64 + frag_kb);

#pragma unroll
    for (int fm = 0; fm < 4; ++fm)
#pragma unroll
      for (int fn = 0; fn < 4; ++fn)
        acc[fm][fn] = __builtin_amdgcn_mfma_f32_16x16x32_bf16(
            af[fm], bf[fn], acc[fm][fn], 0, 0, 0);

    __syncthreads();
  }

#pragma unroll
  for (int fn = 0; fn < 4; ++fn) {
    int n = n0 + wc * 64 + fn * 16 + (lane & 15);
    float bv = bias[n];
#pragma unroll
    for (int fm = 0; fm < 4; ++fm) {
      int mrow = m0 + wr * 64 + fm * 16 + (lane >> 4) * 4;
#pragma unroll
      for (int j = 0; j < 4; ++j)
        __builtin_nontemporal_store(acc[fm][fn][j] + bv,
                                    &C[(size_t)(mrow + j) * OC + n]);
    }
  }
}

// ---------------------------------------------------------------------------
// Fallback (ws too small): round-3 verified fused kernel
// ---------------------------------------------------------------------------
__global__ __launch_bounds__(256) void w4_gemm_fused_f32(
    const float* __restrict__ A, const int* __restrict__ Q,
    const float* __restrict__ scales, const float* __restrict__ zeros,
    const float* __restrict__ bias, float* __restrict__ C) {
  __shared__ __hip_bfloat16 As[128 * 32];
  __shared__ __hip_bfloat16 Bs[128 * 32];
  const int NBN = OC / 128;
  const int NBLK = (MTOT / 128) * NBN;
  int bid = blockIdx.x;
  int swz = (bid & 7) * (NBLK >> 3) + (bid >> 3);
  int bm = swz / NBN, bn = swz % NBN;
  const int m0 = bm * 128, n0 = bn * 128;
  const int tid = threadIdx.x;
  const int wid = tid >> 6, lane = tid & 63;
  const int wr = wid >> 1, wc = wid & 1;
  const int row = tid >> 1;
  const int kh  = (tid & 1) * 16;
  const float* arow = A + (size_t)(m0 + row) * IC + kh;
  const int*   qrow = Q + (size_t)(n0 + row) * IC + kh;
  const int    nrow = n0 + row;
  const int a_row = wr * 64 + (lane & 15);
  const int b_row = wc * 64 + (lane & 15);
  const int frag_kb = (lane >> 4) * 16;
  floatx4 acc[4][4];
#pragma unroll
  for (int i = 0; i < 4; ++i)
#pragma unroll
    for (int j = 0; j < 4; ++j)
      acc[i][j] = (floatx4){0.f, 0.f, 0.f, 0.f};
  for (int k0 = 0; k0 < IC; k0 += 32) {
    float4 a0 = *(const float4*)(arow + k0);
    float4 a1 = *(const float4*)(arow + k0 + 4);
    float4 a2 = *(const float4*)(arow + k0 + 8);
    float4 a3 = *(const float4*)(arow + k0 + 12);
    int4 q0 = *(const int4*)(qrow + k0);
    int4 q1 = *(const int4*)(qrow + k0 + 4);
    int4 q2 = *(const int4*)(qrow + k0 + 8);
    int4 q3 = *(const int4*)(qrow + k0 + 12);
    int g = k0 >> 7;
    float s = scales[(size_t)g * OC + nrow];
    float z = zeros[(size_t)g * OC + nrow];
    union { __hip_bfloat16 h[16]; short8 v[2]; } ua, ub;
    ua.h[0]=__float2bfloat16(a0.x); ua.h[1]=__float2bfloat16(a0.y);
    ua.h[2]=__float2bfloat16(a0.z); ua.h[3]=__float2bfloat16(a0.w);
    ua.h[4]=__float2bfloat16(a1.x); ua.h[5]=__float2bfloat16(a1.y);
    ua.h[6]=__float2bfloat16(a1.z); ua.h[7]=__float2bfloat16(a1.w);
    ua.h[8]=__float2bfloat16(a2.x); ua.h[9]=__float2bfloat16(a2.y);
    ua.h[10]=__float2bfloat16(a2.z); ua.h[11]=__float2bfloat16(a2.w);
    ua.h[12]=__float2bfloat16(a3.x); ua.h[13]=__float2bfloat16(a3.y);
    ua.h[14]=__float2bfloat16(a3.z); ua.h[15]=__float2bfloat16(a3.w);
    ub.h[0]=__float2bfloat16(fmaf((float)q0.x,s,z));
    ub.h[1]=__float2bfloat16(fmaf((float)q0.y,s,z));
    ub.h[2]=__float2bfloat16(fmaf((float)q0.z,s,z));
    ub.h[3]=__float2bfloat16(fmaf((float)q0.w,s,z));
    ub.h[4]=__float2bfloat16(fmaf((float)q1.x,s,z));
    ub.h[5]=__float2bfloat16(fmaf((float)q1.y,s,z));
    ub.h[6]=__float2bfloat16(fmaf((float)q1.z,s,z));
    ub.h[7]=__float2bfloat16(fmaf((float)q1.w,s,z));
    ub.h[8]=__float2bfloat16(fmaf((float)q2.x,s,z));
    ub.h[9]=__float2bfloat16(fmaf((float)q2.y,s,z));
    ub.h[10]=__float2bfloat16(fmaf((float)q2.z,s,z));
    ub.h[11]=__float2bfloat16(fmaf((float)q2.w,s,z));
    ub.h[12]=__float2bfloat16(fmaf((float)q3.x,s,z));
    ub.h[13]=__float2bfloat16(fmaf((float)q3.y,s,z));
    ub.h[14]=__float2bfloat16(fmaf((float)q3.z,s,z));
    ub.h[15]=__float2bfloat16(fmaf((float)q3.w,s,z));
    *(short8*)(&As[row * 32 + kh])     = ua.v[0];
    *(short8*)(&As[row * 32 + kh + 8]) = ua.v[1];
    *(short8*)(&Bs[row * 32 + kh])     = ub.v[0];
    *(short8*)(&Bs[row * 32 + kh + 8]) = ub.v[1];
    __syncthreads();
    short8 af[4], bf[4];
#pragma unroll
    for (int fm = 0; fm < 4; ++fm)
      af[fm] = *(const short8*)((const char*)As + (a_row + fm*16)*64 + frag_kb);
#pragma unroll
    for (int fn = 0; fn < 4; ++fn)
      bf[fn] = *(const short8*)((const char*)Bs + (b_row + fn*16)*64 + frag_kb);
#pragma unroll
    for (int fm = 0; fm < 4; ++fm)
#pragma unroll
      for (int fn = 0; fn < 4; ++fn)
        acc[fm][fn] = __builtin_amdgcn_mfma_f32_16x16x32_bf16(
            af[fm], bf[fn], acc[fm][fn], 0, 0, 0);
    __syncthreads();
  }
#pragma unroll
  for (int fn = 0; fn < 4; ++fn) {
    int n = n0 + wc * 64 + fn * 16 + (lane & 15);
    float bv = bias[n];
#pragma unroll
    for (int fm = 0; fm < 4; ++fm) {
      int mrow = m0 + wr * 64 + fm * 16 + (lane >> 4) * 4;
#pragma unroll
      for (int j = 0; j < 4; ++j)
        C[(size_t)(mrow + j) * OC + n] = acc[fm][fn][j] + bv;
    }
  }
}

extern "C" void kernel_launch(void* const* d_in, const int* in_sizes, int n_in,
                              void* d_out, int out_size, void* d_ws, size_t ws_size,
                              hipStream_t stream) {
  const float* x      = (const float*)d_in[0];
  const int*   qw     = (const int*)d_in[1];
  const float* scales = (const float*)d_in[2];
  const float* szeros = (const float*)d_in[3];
  const float* bias   = (const float*)d_in[4];
  float* out = (float*)d_out;

  const size_t wbytes = (size_t)OC * IC * 2;
  const size_t xbytes = (size_t)MTOT * IC * 2;

  if (ws_size >= wbytes + xbytes) {
    __hip_bfloat16* W  = (__hip_bfloat16*)d_ws;
    __hip_bfloat16* Xb = (__hip_bfloat16*)((char*)d_ws + wbytes);
    cvt_x_kernel<<<16384, 256, 0, stream>>>(x, Xb);
    dequant_kernel<<<22016, 256, 0, stream>>>(qw, scales, szeros, W);
    gemm_bt_tail<<<NBLK_B, 256, 0, stream>>>(Xb, W, bias, out);
    gemm_8phase<<<NBLK_A, 512, 0, stream>>>(Xb, W, bias, out);
  } else {
    w4_gemm_fused_f32<<<5504, 256, 0, stream>>>(x, qw, scales, szeros, bias, out);
  }
}

// Round 13
// 769.017 us; speedup vs baseline: 1.0108x; 1.0049x over previous
//
#include <hip/hip_runtime.h>
#include <hip/hip_bf16.h>

#define IC 4096
#define OC 11008
#define MTOT 8192

#define BM 256
#define BN 256
#define BK 64
#define NT (IC / BK)      // 64 K-tiles
#define LDSBUF 65536      // one buffer: A 32 KB + B 32 KB (tail uses 48 KB)
#define BOFF 32768

// Unified grid: 192 tail half-tiles (256x128, cols 10240..11007) first,
// then 1280 main tiles (256x256, cols 0..10239). Worst CU: 5 full + 1 half
// = 5.5 rounds (vs 6 for any all-full-tile assignment).
#define NTAIL 192         // 32 bm x 6 bn(128-wide)
#define NBN_A 40
#define NBLK_A 1280       // 32 x 40, = 5.0 exact rounds
#define NBASE_T 10240

typedef __attribute__((ext_vector_type(8))) short short8;
typedef __attribute__((ext_vector_type(4))) float floatx4;

__device__ __forceinline__ void async_copy16(const void* g, void* l) {
  __builtin_amdgcn_global_load_lds(
      (const __attribute__((address_space(1))) void*)g,
      (__attribute__((address_space(3))) void*)l, 16, 0, 0);
}

#define CFENCE() asm volatile("" ::: "memory")
#define BARRIER() do { CFENCE(); __builtin_amdgcn_s_barrier(); CFENCE(); } while (0)

// ---------------------------------------------------------------------------
// Pass 1a: x f32 -> bf16
// ---------------------------------------------------------------------------
__global__ __launch_bounds__(256) void cvt_x_kernel(
    const float* __restrict__ X, __hip_bfloat16* __restrict__ Xb) {
  size_t base = ((size_t)blockIdx.x * 256 + threadIdx.x) * 8;
  float4 a0 = *(const float4*)(X + base);
  float4 a1 = *(const float4*)(X + base + 4);
  union { __hip_bfloat16 h[8]; short8 v; } u;
  u.h[0] = __float2bfloat16(a0.x); u.h[1] = __float2bfloat16(a0.y);
  u.h[2] = __float2bfloat16(a0.z); u.h[3] = __float2bfloat16(a0.w);
  u.h[4] = __float2bfloat16(a1.x); u.h[5] = __float2bfloat16(a1.y);
  u.h[6] = __float2bfloat16(a1.z); u.h[7] = __float2bfloat16(a1.w);
  *(short8*)(Xb + base) = u.v;
}

// ---------------------------------------------------------------------------
// Pass 1b: dequant Q int32 -> bf16 W [OC][IC]
// ---------------------------------------------------------------------------
__global__ __launch_bounds__(256) void dequant_kernel(
    const int* __restrict__ Q, const float* __restrict__ scales,
    const float* __restrict__ zeros, __hip_bfloat16* __restrict__ W) {
  size_t base = ((size_t)blockIdx.x * 256 + threadIdx.x) * 8;
  int o = (int)(base >> 12);
  int g = ((int)(base & 4095)) >> 7;
  float s = scales[(size_t)g * OC + o];
  float z = zeros[(size_t)g * OC + o];
  int4 q0 = *(const int4*)(Q + base);
  int4 q1 = *(const int4*)(Q + base + 4);
  union { __hip_bfloat16 h[8]; short8 v; } u;
  u.h[0] = __float2bfloat16(fmaf((float)q0.x, s, z));
  u.h[1] = __float2bfloat16(fmaf((float)q0.y, s, z));
  u.h[2] = __float2bfloat16(fmaf((float)q0.z, s, z));
  u.h[3] = __float2bfloat16(fmaf((float)q0.w, s, z));
  u.h[4] = __float2bfloat16(fmaf((float)q1.x, s, z));
  u.h[5] = __float2bfloat16(fmaf((float)q1.y, s, z));
  u.h[6] = __float2bfloat16(fmaf((float)q1.z, s, z));
  u.h[7] = __float2bfloat16(fmaf((float)q1.w, s, z));
  *(short8*)(W + base) = u.v;
}

// ---------------------------------------------------------------------------
// Unified GEMM: 8-wave 4-phase pipelined, 16x16x32 MFMA, XOR-swizzled LDS.
// bid < NTAIL: 256x128 tail half-tile (2 B-units, acc[8][2], vmcnt 4/0)
// bid >= NTAIL: 256x256 main tile (exact round-5 body, vmcnt 6/0)
// ---------------------------------------------------------------------------
__global__ __launch_bounds__(512, 2) void gemm_8phase(
    const __hip_bfloat16* __restrict__ A,   // [MTOT][IC] bf16
    const __hip_bfloat16* __restrict__ B,   // [OC][IC] bf16
    const float* __restrict__ bias,         // [OC] f32
    float* __restrict__ C) {                // [MTOT][OC] f32
  __shared__ char lds[2 * LDSBUF];          // 128 KB

  const int tid  = threadIdx.x;
  const int lane = tid & 63;
  const int wid  = tid >> 6;
  const int wr = wid >> 2, wc = wid & 3;    // 2x4 wave grid

  // staging geometry: unit = 64 rows x 128 B = 8 KB = 1 load/thread
  const int srl   = tid >> 3;               // row within unit (0..63)
  const int scph  = (tid & 7) << 4;         // physical col byte
  const int sclog = scph ^ ((srl & 7) << 4);// pre-swizzled logical col byte
  const size_t UROW = (size_t)64 * IC * 2;  // global byte stride per unit
  const int sdst = tid * 16;                // linear LDS dest within unit

  // fragment-read geometry (16x16x32; lane: row l&15, k (l>>4)*8)
  const int l15  = lane & 15;
  const int hi16 = ((lane >> 4) & 3) << 4;
  const int swzl = (lane & 7) << 4;
  const int ck0  = hi16 ^ swzl;             // col byte for kk=0 (kk=1: ^64)
  const int aRowB = (wr * 128 + l15) * 128; // row byte offset in A region

  const int bid = blockIdx.x;

  if (bid < NTAIL) {
    // =====================================================================
    // TAIL: 256x128 tile. B region = 128 rows = 2 units (16 KB).
    // Wave owns 128x32 (2 fn frags). 8 MFMA/phase.
    // Ledger: carry 4 = t+1{B0,B1,A0,A2}; p0 +2(t+1 A1,A3); p1 +2(t+2 B);
    // p2 +2(t+2 A0,A2); end vmcnt(4) drains 6 oldest = t+1 complete.
    // Staging safety: B read p0 (drained p0-lgkmcnt) -> staged p1;
    // A0/A2 last read p1 (rows 32-63) -> staged p2; A1/A3 other buffer.
    // =====================================================================
    const int bm = bid / 6, bn = bid % 6;   // 32 x 6
    const int m0 = bm * BM, n0 = NBASE_T + bn * 128;

    const char* gA = (const char*)A + ((size_t)(m0 + srl) * IC) * 2 + sclog;
    const char* gB = (const char*)B + ((size_t)(n0 + srl) * IC) * 2 + sclog;
    const int bRowB = (wc * 32 + l15) * 128;

    floatx4 acc[8][2];
#pragma unroll
    for (int i = 0; i < 8; ++i)
#pragma unroll
      for (int j = 0; j < 2; ++j)
        acc[i][j] = (floatx4){0.f, 0.f, 0.f, 0.f};

    // prologue: tile0 A0-3,B0-1 (6) + tile1 B0-1,A0,A2 (4)
#pragma unroll
    for (int u = 0; u < 4; ++u)
      async_copy16(gA + u * UROW, lds + u * 8192 + sdst);
#pragma unroll
    for (int u = 0; u < 2; ++u)
      async_copy16(gB + u * UROW, lds + BOFF + u * 8192 + sdst);
#pragma unroll
    for (int u = 0; u < 2; ++u)
      async_copy16(gB + u * UROW + 128, lds + LDSBUF + BOFF + u * 8192 + sdst);
    async_copy16(gA + 0 * UROW + 128, lds + LDSBUF + 0 * 8192 + sdst);
    async_copy16(gA + 2 * UROW + 128, lds + LDSBUF + 2 * 8192 + sdst);
    asm volatile("s_waitcnt vmcnt(4)" ::: "memory");  // tile0 landed
    BARRIER();

    for (int t = 0; t < NT; ++t) {
      const int par = t & 1;
      char* curA = lds + par * LDSBUF;
      char* curB = curA + BOFF;
      char* nxtA = lds + (par ^ 1) * LDSBUF;
      const char* gAt1 = gA + (size_t)(t + 1) * 128;
      const char* gAt2 = gA + (size_t)(t + 2) * 128;
      const char* gBt2 = gB + (size_t)(t + 2) * 128;
      const bool s1 = (t + 1 < NT), s2 = (t + 2 < NT);

      const char* pa = curA + aRowB;
      const char* pb = curB + bRowB;
      short8 bfr[2][2];

#define MFMA8T(P, AF0, AF1, AF2, AF3)                                        \
      BARRIER();                                                             \
      asm volatile("s_waitcnt lgkmcnt(0)" ::: "memory");                     \
      __builtin_amdgcn_s_setprio(1);                                         \
      _Pragma("unroll")                                                      \
      for (int fn = 0; fn < 2; ++fn) {                                       \
        acc[2*(P)][fn]   = __builtin_amdgcn_mfma_f32_16x16x32_bf16(          \
            AF0, bfr[fn][0], acc[2*(P)][fn], 0, 0, 0);                       \
        acc[2*(P)][fn]   = __builtin_amdgcn_mfma_f32_16x16x32_bf16(          \
            AF1, bfr[fn][1], acc[2*(P)][fn], 0, 0, 0);                       \
        acc[2*(P)+1][fn] = __builtin_amdgcn_mfma_f32_16x16x32_bf16(          \
            AF2, bfr[fn][0], acc[2*(P)+1][fn], 0, 0, 0);                     \
        acc[2*(P)+1][fn] = __builtin_amdgcn_mfma_f32_16x16x32_bf16(          \
            AF3, bfr[fn][1], acc[2*(P)+1][fn], 0, 0, 0);                     \
      }                                                                      \
      __builtin_amdgcn_s_setprio(0);

      // phase 0: fm 0-1 (A rows 0-31/128-159); read B frags; stage t+1 A1,A3
      {
        short8 a00 = *(const short8*)(pa + 0 * 2048 + ck0);
        short8 a01 = *(const short8*)(pa + 0 * 2048 + (ck0 ^ 64));
        short8 a10 = *(const short8*)(pa + 1 * 2048 + ck0);
        short8 a11 = *(const short8*)(pa + 1 * 2048 + (ck0 ^ 64));
#pragma unroll
        for (int fn = 0; fn < 2; ++fn) {
          bfr[fn][0] = *(const short8*)(pb + fn * 2048 + ck0);
          bfr[fn][1] = *(const short8*)(pb + fn * 2048 + (ck0 ^ 64));
        }
        if (s1) {
          async_copy16(gAt1 + 1 * UROW, nxtA + 1 * 8192 + sdst);
          async_copy16(gAt1 + 3 * UROW, nxtA + 3 * 8192 + sdst);
        }
        MFMA8T(0, a00, a01, a10, a11);
        BARRIER();
      }
      // phase 1: fm 2-3; stage t+2 B0,B1
      {
        short8 a00 = *(const short8*)(pa + 2 * 2048 + ck0);
        short8 a01 = *(const short8*)(pa + 2 * 2048 + (ck0 ^ 64));
        short8 a10 = *(const short8*)(pa + 3 * 2048 + ck0);
        short8 a11 = *(const short8*)(pa + 3 * 2048 + (ck0 ^ 64));
        if (s2) {
          async_copy16(gBt2 + 0 * UROW, curB + 0 * 8192 + sdst);
          async_copy16(gBt2 + 1 * UROW, curB + 1 * 8192 + sdst);
        }
        MFMA8T(1, a00, a01, a10, a11);
        BARRIER();
      }
      // phase 2: fm 4-5; stage t+2 A0,A2
      {
        short8 a00 = *(const short8*)(pa + 4 * 2048 + ck0);
        short8 a01 = *(const short8*)(pa + 4 * 2048 + (ck0 ^ 64));
        short8 a10 = *(const short8*)(pa + 5 * 2048 + ck0);
        short8 a11 = *(const short8*)(pa + 5 * 2048 + (ck0 ^ 64));
        if (s2) {
          async_copy16(gAt2 + 0 * UROW, curA + 0 * 8192 + sdst);
          async_copy16(gAt2 + 2 * UROW, curA + 2 * 8192 + sdst);
        }
        MFMA8T(2, a00, a01, a10, a11);
        BARRIER();
      }
      // phase 3: fm 6-7; end vmcnt
      {
        short8 a00 = *(const short8*)(pa + 6 * 2048 + ck0);
        short8 a01 = *(const short8*)(pa + 6 * 2048 + (ck0 ^ 64));
        short8 a10 = *(const short8*)(pa + 7 * 2048 + ck0);
        short8 a11 = *(const short8*)(pa + 7 * 2048 + (ck0 ^ 64));
        MFMA8T(3, a00, a01, a10, a11);
        // end: s2: 4+2+2+2=10 outstanding, drain 6 oldest (t+1) -> vmcnt(4)
        //      s1 only: 4+2=6 -> vmcnt(0)
        if (s2)      { asm volatile("s_waitcnt vmcnt(4)" ::: "memory"); }
        else if (s1) { asm volatile("s_waitcnt vmcnt(0)" ::: "memory"); }
        BARRIER();
      }
#undef MFMA8T
    }

    // epilogue: fn < 2
#pragma unroll
    for (int fn = 0; fn < 2; ++fn) {
      int n = n0 + wc * 32 + fn * 16 + l15;
      float bv = bias[n];
#pragma unroll
      for (int fm = 0; fm < 8; ++fm) {
        int mrow = m0 + wr * 128 + fm * 16 + ((lane >> 4) << 2);
#pragma unroll
        for (int j = 0; j < 4; ++j)
          C[(size_t)(mrow + j) * OC + n] = acc[fm][fn][j] + bv;
      }
    }
    return;
  }

  // =======================================================================
  // MAIN: 256x256 tile, exact round-5 verified body.
  // =======================================================================
  int mb = bid - NTAIL;
  int swz = (mb & 7) * (NBLK_A >> 3) + (mb >> 3);  // bijective (1280=8*160)
  int bm = swz / NBN_A, bn = swz % NBN_A;
  const int m0 = bm * BM, n0 = bn * BN;

  const char* gA = (const char*)A + ((size_t)(m0 + srl) * IC) * 2 + sclog;
  const char* gB = (const char*)B + ((size_t)(n0 + srl) * IC) * 2 + sclog;
  const int bRowB = (wc * 64 + l15) * 128;

  floatx4 acc[8][4];
#pragma unroll
  for (int i = 0; i < 8; ++i)
#pragma unroll
    for (int j = 0; j < 4; ++j)
      acc[i][j] = (floatx4){0.f, 0.f, 0.f, 0.f};

  // prologue: tile0 complete (8) + tile1 partial (B0-3,A0,A2)
#pragma unroll
  for (int u = 0; u < 4; ++u)
    async_copy16(gA + u * UROW, lds + u * 8192 + sdst);
#pragma unroll
  for (int u = 0; u < 4; ++u)
    async_copy16(gB + u * UROW, lds + BOFF + u * 8192 + sdst);
#pragma unroll
  for (int u = 0; u < 4; ++u)
    async_copy16(gB + u * UROW + 128, lds + LDSBUF + BOFF + u * 8192 + sdst);
  async_copy16(gA + 0 * UROW + 128, lds + LDSBUF + 0 * 8192 + sdst);
  async_copy16(gA + 2 * UROW + 128, lds + LDSBUF + 2 * 8192 + sdst);
  asm volatile("s_waitcnt vmcnt(6)" ::: "memory");  // tile0 landed
  BARRIER();

  for (int t = 0; t < NT; ++t) {
    const int par = t & 1;
    char* curA = lds + par * LDSBUF;
    char* curB = curA + BOFF;
    char* nxtA = lds + (par ^ 1) * LDSBUF;
    const char* gAt1 = gA + (size_t)(t + 1) * 128;
    const char* gAt2 = gA + (size_t)(t + 2) * 128;
    const char* gBt2 = gB + (size_t)(t + 2) * 128;
    const bool s1 = (t + 1 < NT), s2 = (t + 2 < NT);

    const char* pa = curA + aRowB;
    const char* pb = curB + bRowB;
    short8 bfr[4][2];

#define MFMA16(P, AF0, AF1, AF2, AF3)                                        \
    BARRIER();                                                               \
    asm volatile("s_waitcnt lgkmcnt(0)" ::: "memory");                       \
    __builtin_amdgcn_s_setprio(1);                                           \
    _Pragma("unroll")                                                        \
    for (int fn = 0; fn < 4; ++fn) {                                         \
      acc[2*(P)][fn]   = __builtin_amdgcn_mfma_f32_16x16x32_bf16(            \
          AF0, bfr[fn][0], acc[2*(P)][fn], 0, 0, 0);                         \
      acc[2*(P)][fn]   = __builtin_amdgcn_mfma_f32_16x16x32_bf16(            \
          AF1, bfr[fn][1], acc[2*(P)][fn], 0, 0, 0);                         \
      acc[2*(P)+1][fn] = __builtin_amdgcn_mfma_f32_16x16x32_bf16(            \
          AF2, bfr[fn][0], acc[2*(P)+1][fn], 0, 0, 0);                       \
      acc[2*(P)+1][fn] = __builtin_amdgcn_mfma_f32_16x16x32_bf16(            \
          AF3, bfr[fn][1], acc[2*(P)+1][fn], 0, 0, 0);                       \
    }                                                                        \
    __builtin_amdgcn_s_setprio(0);

    // phase 0: fm 0-1; read all B frags; stage t+1 A1,A3
    {
      short8 a00 = *(const short8*)(pa + 0 * 2048 + ck0);
      short8 a01 = *(const short8*)(pa + 0 * 2048 + (ck0 ^ 64));
      short8 a10 = *(const short8*)(pa + 1 * 2048 + ck0);
      short8 a11 = *(const short8*)(pa + 1 * 2048 + (ck0 ^ 64));
#pragma unroll
      for (int fn = 0; fn < 4; ++fn) {
        bfr[fn][0] = *(const short8*)(pb + fn * 2048 + ck0);
        bfr[fn][1] = *(const short8*)(pb + fn * 2048 + (ck0 ^ 64));
      }
      if (s1) {
        async_copy16(gAt1 + 1 * UROW, nxtA + 1 * 8192 + sdst);
        async_copy16(gAt1 + 3 * UROW, nxtA + 3 * 8192 + sdst);
      }
      MFMA16(0, a00, a01, a10, a11);
      BARRIER();
    }
    // phase 1: fm 2-3; stage t+2 B0,B1
    {
      short8 a00 = *(const short8*)(pa + 2 * 2048 + ck0);
      short8 a01 = *(const short8*)(pa + 2 * 2048 + (ck0 ^ 64));
      short8 a10 = *(const short8*)(pa + 3 * 2048 + ck0);
      short8 a11 = *(const short8*)(pa + 3 * 2048 + (ck0 ^ 64));
      if (s2) {
        async_copy16(gBt2 + 0 * UROW, curB + 0 * 8192 + sdst);
        async_copy16(gBt2 + 1 * UROW, curB + 1 * 8192 + sdst);
      }
      MFMA16(1, a00, a01, a10, a11);
      BARRIER();
    }
    // phase 2: fm 4-5; stage t+2 B2,B3
    {
      short8 a00 = *(const short8*)(pa + 4 * 2048 + ck0);
      short8 a01 = *(const short8*)(pa + 4 * 2048 + (ck0 ^ 64));
      short8 a10 = *(const short8*)(pa + 5 * 2048 + ck0);
      short8 a11 = *(const short8*)(pa + 5 * 2048 + (ck0 ^ 64));
      if (s2) {
        async_copy16(gBt2 + 2 * UROW, curB + 2 * 8192 + sdst);
        async_copy16(gBt2 + 3 * UROW, curB + 3 * 8192 + sdst);
      }
      MFMA16(2, a00, a01, a10, a11);
      BARRIER();
    }
    // phase 3: fm 6-7; stage t+2 A0,A2
    {
      short8 a00 = *(const short8*)(pa + 6 * 2048 + ck0);
      short8 a01 = *(const short8*)(pa + 6 * 2048 + (ck0 ^ 64));
      short8 a10 = *(const short8*)(pa + 7 * 2048 + ck0);
      short8 a11 = *(const short8*)(pa + 7 * 2048 + (ck0 ^ 64));
      if (s2) {
        async_copy16(gAt2 + 0 * UROW, curA + 0 * 8192 + sdst);
        async_copy16(gAt2 + 2 * UROW, curA + 2 * 8192 + sdst);
      }
      MFMA16(3, a00, a01, a10, a11);
      if (s2)      { asm volatile("s_waitcnt vmcnt(6)" ::: "memory"); }
      else if (s1) { asm volatile("s_waitcnt vmcnt(0)" ::: "memory"); }
      BARRIER();
    }
#undef MFMA16
  }

  // epilogue: bias + f32 store
#pragma unroll
  for (int fn = 0; fn < 4; ++fn) {
    int n = n0 + wc * 64 + fn * 16 + l15;
    float bv = bias[n];
#pragma unroll
    for (int fm = 0; fm < 8; ++fm) {
      int mrow = m0 + wr * 128 + fm * 16 + ((lane >> 4) << 2);
#pragma unroll
      for (int j = 0; j < 4; ++j)
        C[(size_t)(mrow + j) * OC + n] = acc[fm][fn][j] + bv;
    }
  }
}

// ---------------------------------------------------------------------------
// Fallback (ws too small): round-3 verified fused kernel
// ---------------------------------------------------------------------------
__global__ __launch_bounds__(256) void w4_gemm_fused_f32(
    const float* __restrict__ A, const int* __restrict__ Q,
    const float* __restrict__ scales, const float* __restrict__ zeros,
    const float* __restrict__ bias, float* __restrict__ C) {
  __shared__ __hip_bfloat16 As[128 * 32];
  __shared__ __hip_bfloat16 Bs[128 * 32];
  const int NBN = OC / 128;
  const int NBLK = (MTOT / 128) * NBN;
  int bid = blockIdx.x;
  int swz = (bid & 7) * (NBLK >> 3) + (bid >> 3);
  int bm = swz / NBN, bn = swz % NBN;
  const int m0 = bm * 128, n0 = bn * 128;
  const int tid = threadIdx.x;
  const int wid = tid >> 6, lane = tid & 63;
  const int wr = wid >> 1, wc = wid & 1;
  const int row = tid >> 1;
  const int kh  = (tid & 1) * 16;
  const float* arow = A + (size_t)(m0 + row) * IC + kh;
  const int*   qrow = Q + (size_t)(n0 + row) * IC + kh;
  const int    nrow = n0 + row;
  const int a_row = wr * 64 + (lane & 15);
  const int b_row = wc * 64 + (lane & 15);
  const int frag_kb = (lane >> 4) * 16;
  floatx4 acc[4][4];
#pragma unroll
  for (int i = 0; i < 4; ++i)
#pragma unroll
    for (int j = 0; j < 4; ++j)
      acc[i][j] = (floatx4){0.f, 0.f, 0.f, 0.f};
  for (int k0 = 0; k0 < IC; k0 += 32) {
    float4 a0 = *(const float4*)(arow + k0);
    float4 a1 = *(const float4*)(arow + k0 + 4);
    float4 a2 = *(const float4*)(arow + k0 + 8);
    float4 a3 = *(const float4*)(arow + k0 + 12);
    int4 q0 = *(const int4*)(qrow + k0);
    int4 q1 = *(const int4*)(qrow + k0 + 4);
    int4 q2 = *(const int4*)(qrow + k0 + 8);
    int4 q3 = *(const int4*)(qrow + k0 + 12);
    int g = k0 >> 7;
    float s = scales[(size_t)g * OC + nrow];
    float z = zeros[(size_t)g * OC + nrow];
    union { __hip_bfloat16 h[16]; short8 v[2]; } ua, ub;
    ua.h[0]=__float2bfloat16(a0.x); ua.h[1]=__float2bfloat16(a0.y);
    ua.h[2]=__float2bfloat16(a0.z); ua.h[3]=__float2bfloat16(a0.w);
    ua.h[4]=__float2bfloat16(a1.x); ua.h[5]=__float2bfloat16(a1.y);
    ua.h[6]=__float2bfloat16(a1.z); ua.h[7]=__float2bfloat16(a1.w);
    ua.h[8]=__float2bfloat16(a2.x); ua.h[9]=__float2bfloat16(a2.y);
    ua.h[10]=__float2bfloat16(a2.z); ua.h[11]=__float2bfloat16(a2.w);
    ua.h[12]=__float2bfloat16(a3.x); ua.h[13]=__float2bfloat16(a3.y);
    ua.h[14]=__float2bfloat16(a3.z); ua.h[15]=__float2bfloat16(a3.w);
    ub.h[0]=__float2bfloat16(fmaf((float)q0.x,s,z));
    ub.h[1]=__float2bfloat16(fmaf((float)q0.y,s,z));
    ub.h[2]=__float2bfloat16(fmaf((float)q0.z,s,z));
    ub.h[3]=__float2bfloat16(fmaf((float)q0.w,s,z));
    ub.h[4]=__float2bfloat16(fmaf((float)q1.x,s,z));
    ub.h[5]=__float2bfloat16(fmaf((float)q1.y,s,z));
    ub.h[6]=__float2bfloat16(fmaf((float)q1.z,s,z));
    ub.h[7]=__float2bfloat16(fmaf((float)q1.w,s,z));
    ub.h[8]=__float2bfloat16(fmaf((float)q2.x,s,z));
    ub.h[9]=__float2bfloat16(fmaf((float)q2.y,s,z));
    ub.h[10]=__float2bfloat16(fmaf((float)q2.z,s,z));
    ub.h[11]=__float2bfloat16(fmaf((float)q2.w,s,z));
    ub.h[12]=__float2bfloat16(fmaf((float)q3.x,s,z));
    ub.h[13]=__float2bfloat16(fmaf((float)q3.y,s,z));
    ub.h[14]=__float2bfloat16(fmaf((float)q3.z,s,z));
    ub.h[15]=__float2bfloat16(fmaf((float)q3.w,s,z));
    *(short8*)(&As[row * 32 + kh])     = ua.v[0];
    *(short8*)(&As[row * 32 + kh + 8]) = ua.v[1];
    *(short8*)(&Bs[row * 32 + kh])     = ub.v[0];
    *(short8*)(&Bs[row * 32 + kh + 8]) = ub.v[1];
    __syncthreads();
    short8 af[4], bf[4];
#pragma unroll
    for (int fm = 0; fm < 4; ++fm)
      af[fm] = *(const short8*)((const char*)As + (a_row + fm*16)*64 + frag_kb);
#pragma unroll
    for (int fn = 0; fn < 4; ++fn)
      bf[fn] = *(const short8*)((const char*)Bs + (b_row + fn*16)*64 + frag_kb);
#pragma unroll
    for (int fm = 0; fm < 4; ++fm)
#pragma unroll
      for (int fn = 0; fn < 4; ++fn)
        acc[fm][fn] = __builtin_amdgcn_mfma_f32_16x16x32_bf16(
            af[fm], bf[fn], acc[fm][fn], 0, 0, 0);
    __syncthreads();
  }
#pragma unroll
  for (int fn = 0; fn < 4; ++fn) {
    int n = n0 + wc * 64 + fn * 16 + (lane & 15);
    float bv = bias[n];
#pragma unroll
    for (int fm = 0; fm < 4; ++fm) {
      int mrow = m0 + wr * 64 + fm * 16 + (lane >> 4) * 4;
#pragma unroll
      for (int j = 0; j < 4; ++j)
        C[(size_t)(mrow + j) * OC + n] = acc[fm][fn][j] + bv;
    }
  }
}

extern "C" void kernel_launch(void* const* d_in, const int* in_sizes, int n_in,
                              void* d_out, int out_size, void* d_ws, size_t ws_size,
                              hipStream_t stream) {
  const float* x      = (const float*)d_in[0];
  const int*   qw     = (const int*)d_in[1];
  const float* scales = (const float*)d_in[2];
  const float* szeros = (const float*)d_in[3];
  const float* bias   = (const float*)d_in[4];
  float* out = (float*)d_out;

  const size_t wbytes = (size_t)OC * IC * 2;
  const size_t xbytes = (size_t)MTOT * IC * 2;

  if (ws_size >= wbytes + xbytes) {
    __hip_bfloat16* W  = (__hip_bfloat16*)d_ws;
    __hip_bfloat16* Xb = (__hip_bfloat16*)((char*)d_ws + wbytes);
    cvt_x_kernel<<<16384, 256, 0, stream>>>(x, Xb);
    dequant_kernel<<<22016, 256, 0, stream>>>(qw, scales, szeros, W);
    gemm_8phase<<<NTAIL + NBLK_A, 512, 0, stream>>>(Xb, W, bias, out);
  } else {
    w4_gemm_fused_f32<<<5504, 256, 0, stream>>>(x, qw, scales, szeros, bias, out);
  }
}